// Round 3
// baseline (289.087 us; speedup 1.0000x reference)
//
#include <hip/hip_runtime.h>

// MultiRegionalFusionModule: out[b,t,s,f] = tgt[b,t,s,f] +
//   sum_k softmax_k(corr[tci[b,t], ri[k]]) * rv[b,k,f,s]
// B=8 T=32 S=512 F=128 K=64 N=200, fp32.
//
// R1/R2 post-mortem: both ~114us regardless of occupancy -> VMEM-issue
// bound (~16 cyc per 64-lane vmem instr). R3: every global access is
// dwordx4 (16B/lane). 512-thread blocks (8 waves x 4 t), S_TILE=64,
// F_TILE=16; rv float4 along s, epilogue float4 along f via per-wave
// LDS transpose. VMEM instrs 2.6M -> ~1.2M chip-wide.

constexpr int Bn = 8, Tn = 32, Sn = 512, Fn = 128, Kn = 64, Nn = 200;
constexpr int S_TILE = 64;
constexpr int F_TILE = 16;
// grid = Bn * (Sn/S_TILE) * (Fn/F_TILE) = 8*8*8 = 512 blocks of 512 thr
// = exactly 2 blocks/CU; LDS 50KB/block -> both fit (100KB < 160KB).

__global__ __launch_bounds__(512, 4)
void mrf_kernel(const float* __restrict__ tgt,
                const float* __restrict__ rv,
                const float* __restrict__ corr,
                const int*   __restrict__ tci,
                const int*   __restrict__ ri,
                float*       __restrict__ out)
{
    // attnT rows padded to 36 floats so float4 read at t0 (mult of 4) is
    // 16B-aligned (36*4=144B, 144%16==0). Read is wave-broadcast (free).
    __shared__ float attnT[Kn][36];
    // per-wave transpose tile; rows 16+4=20 floats keep float4 alignment
    // (80B). 8 waves * 64 * 20 * 4B = 40KB.
    __shared__ float etile[8][S_TILE][20];

    const int tid  = threadIdx.x;
    const int w    = tid >> 6;    // wave 0..7 -> t chunk of 4
    const int lane = tid & 63;

    const int bid = blockIdx.x;
    const int b  = bid >> 6;
    const int sb = (bid >> 3) & 7;
    const int fb = bid & 7;
    const int s0 = sb * S_TILE;
    const int f0 = fb * F_TILE;

    // ---- prologue: softmax over K (lane = k); wave w -> t = 4w..4w+3 ----
    {
        const int rik = ri[lane];
        #pragma unroll
        for (int j = 0; j < 4; ++j) {
            const int t   = w * 4 + j;
            const int row = tci[b * Tn + t];
            float c = corr[row * Nn + rik];
            float m = c;
            #pragma unroll
            for (int off = 32; off; off >>= 1)
                m = fmaxf(m, __shfl_xor(m, off));
            float e = __expf(c - m);
            float s = e;
            #pragma unroll
            for (int off = 32; off; off >>= 1)
                s += __shfl_xor(s, off);
            attnT[lane][t] = e / s;
        }
    }
    __syncthreads();

    // ---- main loop over k ----
    // lane covers: s = s0 + sg*4 .. +3 (float4), f = f0 + jj*4 + fr
    const int t0 = w * 4;
    const int sg = lane & 15;     // s-group of 4
    const int fr = lane >> 4;     // 0..3, f offset within quad

    float acc[4][4][4];           // [jj=f quad][c=s within float4][tt]
    #pragma unroll
    for (int jj = 0; jj < 4; ++jj)
        #pragma unroll
        for (int c = 0; c < 4; ++c)
            #pragma unroll
            for (int tt = 0; tt < 4; ++tt)
                acc[jj][c][tt] = 0.0f;

    // rv index: ((b*K + k)*F + f)*S + s
    const float* rvp = rv + ((size_t)(b * Kn) * Fn + f0 + fr) * (size_t)Sn
                          + s0 + sg * 4;

    #pragma unroll 2
    for (int k = 0; k < Kn; ++k) {
        const float4 a = *(const float4*)&attnT[k][t0];   // broadcast
        const float* p = rvp + (size_t)k * Fn * Sn;
        float4 v[4];
        #pragma unroll
        for (int jj = 0; jj < 4; ++jj)
            v[jj] = *(const float4*)(p + (size_t)(jj * 4) * Sn);
        #pragma unroll
        for (int jj = 0; jj < 4; ++jj) {
            const float* vv = (const float*)&v[jj];
            #pragma unroll
            for (int c = 0; c < 4; ++c) {
                acc[jj][c][0] = fmaf(vv[c], a.x, acc[jj][c][0]);
                acc[jj][c][1] = fmaf(vv[c], a.y, acc[jj][c][1]);
                acc[jj][c][2] = fmaf(vv[c], a.z, acc[jj][c][2]);
                acc[jj][c][3] = fmaf(vv[c], a.w, acc[jj][c][3]);
            }
        }
    }

    // ---- epilogue: per-wave LDS transpose + residual, all float4 ----
    const int fq = lane & 3;      // f quad for read-back/store
    const int sr = lane >> 2;     // s row group (16 rows per instr)
    for (int tt = 0; tt < 4; ++tt) {
        #pragma unroll
        for (int jj = 0; jj < 4; ++jj)
            #pragma unroll
            for (int c = 0; c < 4; ++c)
                etile[w][sg * 4 + c][jj * 4 + fr] = acc[jj][c][tt];
        __syncthreads();
        const int t = t0 + tt;
        const size_t rowbase = (((size_t)(b * Tn + t)) * Sn + s0) * Fn + f0;
        #pragma unroll
        for (int si = 0; si < 4; ++si) {
            const int ss = si * 16 + sr;
            const float4 e  = *(const float4*)&etile[w][ss][fq * 4];
            const size_t off = rowbase + (size_t)ss * Fn + fq * 4;
            const float4 tg = *(const float4*)(tgt + off);
            float4 o;
            o.x = tg.x + e.x; o.y = tg.y + e.y;
            o.z = tg.z + e.z; o.w = tg.w + e.w;
            *(float4*)(out + off) = o;    // 16 rows x 64B segments
        }
        __syncthreads();
    }
}

extern "C" void kernel_launch(void* const* d_in, const int* in_sizes, int n_in,
                              void* d_out, int out_size, void* d_ws, size_t ws_size,
                              hipStream_t stream)
{
    const float* tgt  = (const float*)d_in[0];   // [B,T,S,F]
    const float* rv   = (const float*)d_in[1];   // [B,K,F,S]
    const float* corr = (const float*)d_in[2];   // [N,N]
    const int*   tci  = (const int*)d_in[3];     // [B,T]
    const int*   ri   = (const int*)d_in[4];     // [K]
    float*       out  = (float*)d_out;           // [B,T,S,F]

    dim3 grid(Bn * (Sn / S_TILE) * (Fn / F_TILE));  // 512
    dim3 block(512);
    hipLaunchKernelGGL(mrf_kernel, grid, block, 0, stream,
                       tgt, rv, corr, tci, ri, out);
}